// Round 6
// baseline (83.660 us; speedup 1.0000x reference)
//
#include <hip/hip_runtime.h>
#include <cstdint>

// Chamfer loss: B=8, N=M=4096, C=3, fp32 in, scalar fp32 out.
// Round 6: scalar-pipe target fetch. Targets pre-transformed (prep) to
// pair-interleaved {-2x0,-2x1,-2y0,-2y1},{-2z0,-2z1,w0,w1} and read through
// constant address space 4 (uniform address -> s_load, 32 B/wave/group vs
// 1024 B/wave/group of DS broadcast). Inner loop pure packed-fp32 VALU:
// 3 pk_fma + 1 min3 per 2 targets per query. atomicMin epilogue (proven free
// in R3/R4) shrinks reduce input to 256 KB.

typedef float v2f __attribute__((ext_vector_type(2)));
typedef float v4f __attribute__((ext_vector_type(4)));
typedef const v4f __attribute__((address_space(4))) cv4f;  // CK-style constant AS

constexpr int B = 8;
constexpr int N = 4096;
constexpr int M = 4096;
constexpr int S = 16;              // target segments per batch
constexpr int TM = M / S;          // 256 targets per segment
constexpr int GPS = TM / 2;        // 128 pair-groups per segment
constexpr int BLOCK = 256;
constexpr int Q = 4;               // query points per thread
constexpr int QPB = BLOCK * Q;     // 1024 queries per block
constexpr int QCH = N / QPB;       // 4 query chunks
constexpr int PAIRS = B * (M / 2); // 16384 pair-groups per point set

// ---- prep: transform+interleave targets, init mins to +inf, zero out ----
__global__ __launch_bounds__(256) void prep_kernel(
    const float* __restrict__ f,    // [B,N,3]
    const float* __restrict__ f_,   // [B,M,3]
    float* __restrict__ pT0,        // [PAIRS*8] from f_ (targets for dir 0)
    float* __restrict__ pT1,        // [PAIRS*8] from f  (targets for dir 1)
    unsigned int* __restrict__ minA,
    unsigned int* __restrict__ minB,
    float* __restrict__ out)
{
    const int t = blockIdx.x * 256 + threadIdx.x;   // 0 .. 2*PAIRS-1 (=2*B*N-? no: 32768)
    const int sel = t / PAIRS;                      // 0 -> f_, 1 -> f
    const int p   = t - sel * PAIRS;
    const float* src = sel ? f : f_;
    float* dst = sel ? pT1 : pT0;

    const float x0 = src[6 * p + 0], y0 = src[6 * p + 1], z0 = src[6 * p + 2];
    const float x1 = src[6 * p + 3], y1 = src[6 * p + 4], z1 = src[6 * p + 5];

    float4 r0, r1;
    r0.x = -2.0f * x0; r0.y = -2.0f * x1;
    r0.z = -2.0f * y0; r0.w = -2.0f * y1;
    r1.x = -2.0f * z0; r1.y = -2.0f * z1;
    r1.z = x0 * x0 + y0 * y0 + z0 * z0;
    r1.w = x1 * x1 + y1 * y1 + z1 * z1;
    ((float4*)dst)[2 * p]     = r0;
    ((float4*)dst)[2 * p + 1] = r1;

    // t spans exactly B*N = 32768: init both min arrays
    minA[t] = 0x7F800000u;   // +inf bits
    minB[t] = 0x7F800000u;

    if (t == 0) out[0] = 0.0f;
}

// ---- main pair scan: SMEM target stream, atomicMin epilogue ----
__global__ __launch_bounds__(256, 4) void chamfer_dir_kernel(
    const float* __restrict__ f,
    const float* __restrict__ f_,
    const float* __restrict__ pT0,
    const float* __restrict__ pT1,
    unsigned int* __restrict__ minA,
    unsigned int* __restrict__ minB)
{
    const int dir = blockIdx.z;
    const int b   = blockIdx.y;
    const int seg = blockIdx.x & (S - 1);
    const int qc  = blockIdx.x >> 4;

    const float* qsrc = dir ? f_ : f;
    const float* pT   = dir ? pT1 : pT0;
    unsigned int* omin = dir ? minB : minA;

    // wave-uniform, read-only, constant-AS -> s_load on the scalar pipe
    cv4f* tp = (cv4f*)(uintptr_t)(pT + ((size_t)b * (M / 2) + (size_t)seg * GPS) * 8);

    const int qbase = qc * QPB + threadIdx.x;
    const float* qb = qsrc + (size_t)b * N * 3;
    v2f qxv[Q], qyv[Q], qzv[Q];
    float qn[Q];
    #pragma unroll
    for (int j = 0; j < Q; ++j) {
        const int q = qbase + j * BLOCK;
        const float x = qb[3 * q + 0], y = qb[3 * q + 1], z = qb[3 * q + 2];
        qxv[j] = (v2f){x, x};
        qyv[j] = (v2f){y, y};
        qzv[j] = (v2f){z, z};
        qn[j] = x * x + y * y + z * z;
    }

    float m[Q];
    #pragma unroll
    for (int j = 0; j < Q; ++j) m[j] = 3.402823466e+38f;

    #pragma unroll 4
    for (int g = 0; g < GPS; ++g) {
        const v4f r0 = tp[2 * g];       // {-2x0,-2x1,-2y0,-2y1}
        const v4f r1 = tp[2 * g + 1];   // {-2z0,-2z1, w0,  w1}
        const v2f x01 = {r0.x, r0.y};
        const v2f y01 = {r0.z, r0.w};
        const v2f z01 = {r1.x, r1.y};
        const v2f w01 = {r1.z, r1.w};

        #pragma unroll
        for (int j = 0; j < Q; ++j) {
            v2f a = qzv[j] * z01 + w01;     // v_pk_fma_f32
            a = qyv[j] * y01 + a;
            a = qxv[j] * x01 + a;
            m[j] = fminf(fminf(m[j], a.x), a.y);   // v_min3_f32
        }
    }

    #pragma unroll
    for (int j = 0; j < Q; ++j) {
        const float d = m[j] + qn[j];   // >= -1e-7; uint-min ordering error ~1e-7, OK
        atomicMin(&omin[b * N + qbase + j * BLOCK], __float_as_uint(d));
    }
}

// ---- reduce: 256 blocks x 256 threads over 2*B*N = 65536 mins ----
__global__ __launch_bounds__(256) void reduce_out_kernel(
    const unsigned int* __restrict__ mins,   // minA followed by minB
    float* __restrict__ out)
{
    __shared__ float wsum[4];
    const int tid = threadIdx.x;
    const int i = blockIdx.x * 256 + tid;
    float s = __uint_as_float(mins[i]);

    #pragma unroll
    for (int off = 32; off > 0; off >>= 1) s += __shfl_down(s, off, 64);
    if ((tid & 63) == 0) wsum[tid >> 6] = s;
    __syncthreads();
    if (tid == 0) {
        const float v = (wsum[0] + wsum[1]) + (wsum[2] + wsum[3]);
        atomicAdd(out, v * (1.0f / 32768.0f));   // / (B*N), N==M
    }
}

extern "C" void kernel_launch(void* const* d_in, const int* in_sizes, int n_in,
                              void* d_out, int out_size, void* d_ws, size_t ws_size,
                              hipStream_t stream) {
    (void)in_sizes; (void)n_in; (void)out_size; (void)ws_size;
    const float* f  = (const float*)d_in[0];
    const float* f_ = (const float*)d_in[1];
    float* out = (float*)d_out;

    unsigned int* minA = (unsigned int*)d_ws;            // B*N
    unsigned int* minB = minA + (size_t)B * N;           // B*M (contiguous after minA)
    float* pT0 = (float*)(minB + (size_t)B * M);         // PAIRS*8 floats
    float* pT1 = pT0 + (size_t)PAIRS * 8;                // PAIRS*8 floats

    prep_kernel<<<(2 * PAIRS) / 256, 256, 0, stream>>>(f, f_, pT0, pT1, minA, minB, out);

    dim3 grid(QCH * S, B, 2);   // (64, 8, 2) = 1024 blocks
    chamfer_dir_kernel<<<grid, BLOCK, 0, stream>>>(f, f_, pT0, pT1, minA, minB);

    reduce_out_kernel<<<256, 256, 0, stream>>>(minA, out);
}